// Round 2
// baseline (2803.424 us; speedup 1.0000x reference)
//
#include <hip/hip_runtime.h>

#define NV 200000
#define NE 1600000
#define CD 128

__device__ __forceinline__ void fma4(float4& acc, float xs, const float4& wv) {
    acc.x += xs * wv.x;
    acc.y += xs * wv.y;
    acc.z += xs * wv.z;
    acc.w += xs * wv.w;
}

// ---------------- Kernel 1: y = x @ W^T ----------------
// Block: 256 threads, 32 vertices. Each thread computes 4 vertices x 4 channels.
// W is staged transposed into LDS with XOR swizzle so compute reads (float4
// along c) are conflict-free; staging writes are only 4-way conflicted.
__global__ __launch_bounds__(256) void gemm_xwT(const float* __restrict__ x,
                                                const float* __restrict__ Wm,
                                                float* __restrict__ y) {
    __shared__ __align__(16) float Xs[32 * CD];   // 16 KB
    __shared__ __align__(16) float Wt[CD * CD];   // 64 KB, swizzled W^T

    const int t = threadIdx.x;
    const int v0 = blockIdx.x * 32;

    // stage X tile: 1024 float4, linear copy
    {
        const float4* xg4 = reinterpret_cast<const float4*>(x + (size_t)v0 * CD);
        float4* Xs4w = reinterpret_cast<float4*>(Xs);
#pragma unroll
        for (int i = 0; i < 4; ++i) Xs4w[t + i * 256] = xg4[t + i * 256];
    }
    // stage W transposed+swizzled: W[c][k] stored at word
    //   k*128 + 4*((c>>2) ^ (k>>2)) + (c&3)
    {
        const float4* Wg4 = reinterpret_cast<const float4*>(Wm);
#pragma unroll
        for (int i = 0; i < 16; ++i) {
            int idx = t + i * 256;
            int c = idx >> 5;      // W row (channel)
            int kkg = idx & 31;    // float4 index along k
            float4 wv = Wg4[idx];
            int col = 4 * ((c >> 2) ^ kkg) + (c & 3);
            Wt[(4 * kkg + 0) * CD + col] = wv.x;
            Wt[(4 * kkg + 1) * CD + col] = wv.y;
            Wt[(4 * kkg + 2) * CD + col] = wv.z;
            Wt[(4 * kkg + 3) * CD + col] = wv.w;
        }
    }
    __syncthreads();

    const int c4 = t & 31;          // channel block: channels c4*4 .. c4*4+3
    const int vl0 = (t >> 5) * 4;   // local vertex base

    float4 a0 = {0, 0, 0, 0}, a1 = {0, 0, 0, 0}, a2 = {0, 0, 0, 0}, a3 = {0, 0, 0, 0};
    const float4* Xs4 = reinterpret_cast<const float4*>(Xs);
    const float4* Wt4 = reinterpret_cast<const float4*>(Wt);

#pragma unroll 4
    for (int kk = 0; kk < 32; ++kk) {
        const int ws = c4 ^ kk;
        float4 w0 = Wt4[(4 * kk + 0) * 32 + ws];
        float4 w1 = Wt4[(4 * kk + 1) * 32 + ws];
        float4 w2 = Wt4[(4 * kk + 2) * 32 + ws];
        float4 w3 = Wt4[(4 * kk + 3) * 32 + ws];
        float4 x0 = Xs4[(vl0 + 0) * 32 + kk];
        float4 x1 = Xs4[(vl0 + 1) * 32 + kk];
        float4 x2 = Xs4[(vl0 + 2) * 32 + kk];
        float4 x3 = Xs4[(vl0 + 3) * 32 + kk];
        fma4(a0, x0.x, w0); fma4(a0, x0.y, w1); fma4(a0, x0.z, w2); fma4(a0, x0.w, w3);
        fma4(a1, x1.x, w0); fma4(a1, x1.y, w1); fma4(a1, x1.z, w2); fma4(a1, x1.w, w3);
        fma4(a2, x2.x, w0); fma4(a2, x2.y, w1); fma4(a2, x2.z, w2); fma4(a2, x2.w, w3);
        fma4(a3, x3.x, w0); fma4(a3, x3.y, w1); fma4(a3, x3.z, w2); fma4(a3, x3.w, w3);
    }

    float4* y4 = reinterpret_cast<float4*>(y);
    const size_t vbase = (size_t)(v0 + vl0);
    y4[(vbase + 0) * 32 + c4] = a0;
    y4[(vbase + 1) * 32 + c4] = a1;
    y4[(vbase + 2) * 32 + c4] = a2;
    y4[(vbase + 3) * 32 + c4] = a3;
}

// ---------------- Kernel 2: out[v][c] = b[c] ----------------
__global__ __launch_bounds__(256) void bias_fill(const float* __restrict__ b,
                                                 float* __restrict__ out) {
    const int idx = blockIdx.x * 256 + threadIdx.x;   // float4 index
    float4 bv = reinterpret_cast<const float4*>(b)[idx & 31];
    reinterpret_cast<float4*>(out)[idx] = bv;
}

// ---------------- Kernel 3: out[rows[e]] += vals[e] * y[cols[e]] ----------------
// 32 lanes per edge, float4 per lane, 4 f32 HW atomics per lane.
__global__ __launch_bounds__(256) void scatter_edges(const int* __restrict__ rows,
                                                     const int* __restrict__ cols,
                                                     const float* __restrict__ vals,
                                                     const float* __restrict__ y,
                                                     float* __restrict__ out) {
    const int t = threadIdx.x;
    const int e = blockIdx.x * 8 + (t >> 5);
    const int c4 = t & 31;
    const int r = rows[e];
    const int c = cols[e];
    const float v = vals[e];
    float4 yv = reinterpret_cast<const float4*>(y)[(size_t)c * 32 + c4];
    float* o = out + (size_t)r * CD + c4 * 4;
    unsafeAtomicAdd(o + 0, v * yv.x);
    unsafeAtomicAdd(o + 1, v * yv.y);
    unsafeAtomicAdd(o + 2, v * yv.z);
    unsafeAtomicAdd(o + 3, v * yv.w);
}

extern "C" void kernel_launch(void* const* d_in, const int* in_sizes, int n_in,
                              void* d_out, int out_size, void* d_ws, size_t ws_size,
                              hipStream_t stream) {
    const float* x    = (const float*)d_in[0];
    const int*   rows = (const int*)d_in[1];
    const int*   cols = (const int*)d_in[2];
    const float* vals = (const float*)d_in[3];
    const float* Wm   = (const float*)d_in[4];
    const float* b    = (const float*)d_in[5];
    float* out = (float*)d_out;
    float* y   = (float*)d_ws;   // NV*CD floats = 102.4 MB

    gemm_xwT<<<NV / 32, 256, 0, stream>>>(x, Wm, y);                 // 6250 blocks
    bias_fill<<<(NV * CD / 4) / 256, 256, 0, stream>>>(b, out);      // 25000 blocks
    scatter_edges<<<NE / 8, 256, 0, stream>>>(rows, cols, vals, y, out); // 200000 blocks
}

// Round 3
// 416.217 us; speedup vs baseline: 6.7355x; 6.7355x over previous
//
#include <hip/hip_runtime.h>

#define NV 200000
#define NE 1600000
#define CD 128

// ---- workspace layout (bytes) ----
#define Y_OFF   0UL                 // NV*CD floats = 102,400,000
#define CNT_OFF 102400000UL         // NV ints     =     800,000
#define OFF_OFF 103200000UL         // NV+1 ints   (padded to 800,256)
#define CUR_OFF 104000256UL         // NV ints     =     800,000
#define BPR_OFF 104800256UL         // 256 ints
#define SC_OFF  104801280UL         // NE ints     =   6,400,000
#define SV_OFF  111201280UL         // NE floats   =   6,400,000
#define WS_REQ  117601280UL

#define SCAN_BS 1024
#define SCAN_NB ((NV + SCAN_BS - 1) / SCAN_BS)   // 196

__device__ __forceinline__ void fma4(float4& acc, float xs, const float4& wv) {
    acc.x += xs * wv.x;
    acc.y += xs * wv.y;
    acc.z += xs * wv.z;
    acc.w += xs * wv.w;
}

// ---------------- Kernel 1: y = x @ W^T ----------------
__global__ __launch_bounds__(256) void gemm_xwT(const float* __restrict__ x,
                                                const float* __restrict__ Wm,
                                                float* __restrict__ y) {
    __shared__ __align__(16) float Xs[32 * CD];   // 16 KB
    __shared__ __align__(16) float Wt[CD * CD];   // 64 KB, swizzled W^T

    const int t = threadIdx.x;
    const int v0 = blockIdx.x * 32;

    {
        const float4* xg4 = reinterpret_cast<const float4*>(x + (size_t)v0 * CD);
        float4* Xs4w = reinterpret_cast<float4*>(Xs);
#pragma unroll
        for (int i = 0; i < 4; ++i) Xs4w[t + i * 256] = xg4[t + i * 256];
    }
    {
        const float4* Wg4 = reinterpret_cast<const float4*>(Wm);
#pragma unroll
        for (int i = 0; i < 16; ++i) {
            int idx = t + i * 256;
            int c = idx >> 5;
            int kkg = idx & 31;
            float4 wv = Wg4[idx];
            int col = 4 * ((c >> 2) ^ kkg) + (c & 3);
            Wt[(4 * kkg + 0) * CD + col] = wv.x;
            Wt[(4 * kkg + 1) * CD + col] = wv.y;
            Wt[(4 * kkg + 2) * CD + col] = wv.z;
            Wt[(4 * kkg + 3) * CD + col] = wv.w;
        }
    }
    __syncthreads();

    const int c4 = t & 31;
    const int vl0 = (t >> 5) * 4;

    float4 a0 = {0, 0, 0, 0}, a1 = {0, 0, 0, 0}, a2 = {0, 0, 0, 0}, a3 = {0, 0, 0, 0};
    const float4* Xs4 = reinterpret_cast<const float4*>(Xs);
    const float4* Wt4 = reinterpret_cast<const float4*>(Wt);

#pragma unroll 4
    for (int kk = 0; kk < 32; ++kk) {
        const int ws = c4 ^ kk;
        float4 w0 = Wt4[(4 * kk + 0) * 32 + ws];
        float4 w1 = Wt4[(4 * kk + 1) * 32 + ws];
        float4 w2 = Wt4[(4 * kk + 2) * 32 + ws];
        float4 w3 = Wt4[(4 * kk + 3) * 32 + ws];
        float4 x0 = Xs4[(vl0 + 0) * 32 + kk];
        float4 x1 = Xs4[(vl0 + 1) * 32 + kk];
        float4 x2 = Xs4[(vl0 + 2) * 32 + kk];
        float4 x3 = Xs4[(vl0 + 3) * 32 + kk];
        fma4(a0, x0.x, w0); fma4(a0, x0.y, w1); fma4(a0, x0.z, w2); fma4(a0, x0.w, w3);
        fma4(a1, x1.x, w0); fma4(a1, x1.y, w1); fma4(a1, x1.z, w2); fma4(a1, x1.w, w3);
        fma4(a2, x2.x, w0); fma4(a2, x2.y, w1); fma4(a2, x2.z, w2); fma4(a2, x2.w, w3);
        fma4(a3, x3.x, w0); fma4(a3, x3.y, w1); fma4(a3, x3.z, w2); fma4(a3, x3.w, w3);
    }

    float4* y4 = reinterpret_cast<float4*>(y);
    const size_t vbase = (size_t)(v0 + vl0);
    y4[(vbase + 0) * 32 + c4] = a0;
    y4[(vbase + 1) * 32 + c4] = a1;
    y4[(vbase + 2) * 32 + c4] = a2;
    y4[(vbase + 3) * 32 + c4] = a3;
}

// ---------------- CSR build ----------------
__global__ __launch_bounds__(256) void k_hist(const int* __restrict__ rows,
                                              int* __restrict__ counts) {
    int e = blockIdx.x * 256 + threadIdx.x;
    if (e < NE) atomicAdd(&counts[rows[e]], 1);
}

__global__ __launch_bounds__(SCAN_BS) void k_blocksum(const int* __restrict__ counts,
                                                      int* __restrict__ bsum) {
    __shared__ int s[SCAN_BS];
    int t = threadIdx.x;
    int i = blockIdx.x * SCAN_BS + t;
    s[t] = (i < NV) ? counts[i] : 0;
    __syncthreads();
#pragma unroll
    for (int d = SCAN_BS / 2; d > 0; d >>= 1) {
        if (t < d) s[t] += s[t + d];
        __syncthreads();
    }
    if (t == 0) bsum[blockIdx.x] = s[0];
}

__global__ __launch_bounds__(256) void k_scanpart(const int* __restrict__ bsum,
                                                  int* __restrict__ bpre,
                                                  int* __restrict__ offsets) {
    __shared__ int s[256];
    int t = threadIdx.x;
    int v = (t < SCAN_NB) ? bsum[t] : 0;
    s[t] = v;
    __syncthreads();
    for (int d = 1; d < 256; d <<= 1) {
        int add = (t >= d) ? s[t - d] : 0;
        __syncthreads();
        s[t] += add;
        __syncthreads();
    }
    if (t < SCAN_NB) bpre[t] = s[t] - v;   // exclusive
    if (t == 0) offsets[NV] = NE;
}

__global__ __launch_bounds__(SCAN_BS) void k_scan(const int* __restrict__ counts,
                                                  const int* __restrict__ bpre,
                                                  int* __restrict__ offsets,
                                                  int* __restrict__ cursor) {
    __shared__ int s[SCAN_BS];
    int t = threadIdx.x;
    int i = blockIdx.x * SCAN_BS + t;
    int v = (i < NV) ? counts[i] : 0;
    s[t] = v;
    __syncthreads();
    for (int d = 1; d < SCAN_BS; d <<= 1) {
        int add = (t >= d) ? s[t - d] : 0;
        __syncthreads();
        s[t] += add;
        __syncthreads();
    }
    if (i < NV) {
        int excl = s[t] - v + bpre[blockIdx.x];
        offsets[i] = excl;
        cursor[i] = excl;
    }
}

__global__ __launch_bounds__(256) void k_permute(const int* __restrict__ rows,
                                                 const int* __restrict__ cols,
                                                 const float* __restrict__ vals,
                                                 int* __restrict__ cursor,
                                                 int* __restrict__ sc,
                                                 float* __restrict__ sv) {
    int e = blockIdx.x * 256 + threadIdx.x;
    if (e < NE) {
        int r = rows[e];
        int pos = atomicAdd(&cursor[r], 1);
        sc[pos] = cols[e];
        sv[pos] = vals[e];
    }
}

// ---------------- gather-reduce: 1 wave per row ----------------
__global__ __launch_bounds__(256) void k_gather(const int* __restrict__ offsets,
                                                const int* __restrict__ sc,
                                                const float* __restrict__ sv,
                                                const float* __restrict__ y,
                                                const float* __restrict__ b,
                                                float* __restrict__ out) {
    const int wid = threadIdx.x >> 6;
    const int lane = threadIdx.x & 63;
    const int row = blockIdx.x * 4 + wid;
    if (row >= NV) return;

    const float2* y2 = reinterpret_cast<const float2*>(y);
    float2 acc = reinterpret_cast<const float2*>(b)[lane];

    int e = offsets[row];
    const int end = offsets[row + 1];

    for (; e + 2 <= end; e += 2) {
        int c0 = sc[e], c1 = sc[e + 1];
        float v0 = sv[e], v1 = sv[e + 1];
        float2 ya = y2[(size_t)c0 * 64 + lane];
        float2 yb = y2[(size_t)c1 * 64 + lane];
        acc.x += v0 * ya.x + v1 * yb.x;
        acc.y += v0 * ya.y + v1 * yb.y;
    }
    if (e < end) {
        int c0 = sc[e];
        float v0 = sv[e];
        float2 ya = y2[(size_t)c0 * 64 + lane];
        acc.x += v0 * ya.x;
        acc.y += v0 * ya.y;
    }
    reinterpret_cast<float2*>(out)[(size_t)row * 64 + lane] = acc;
}

// ---------------- fallback (round-2 proven path) ----------------
__global__ __launch_bounds__(256) void bias_fill(const float* __restrict__ b,
                                                 float* __restrict__ out) {
    const int idx = blockIdx.x * 256 + threadIdx.x;
    float4 bv = reinterpret_cast<const float4*>(b)[idx & 31];
    reinterpret_cast<float4*>(out)[idx] = bv;
}

__global__ __launch_bounds__(256) void scatter_edges(const int* __restrict__ rows,
                                                     const int* __restrict__ cols,
                                                     const float* __restrict__ vals,
                                                     const float* __restrict__ y,
                                                     float* __restrict__ out) {
    const int t = threadIdx.x;
    const int e = blockIdx.x * 8 + (t >> 5);
    const int c4 = t & 31;
    const int r = rows[e];
    const int c = cols[e];
    const float v = vals[e];
    float4 yv = reinterpret_cast<const float4*>(y)[(size_t)c * 32 + c4];
    float* o = out + (size_t)r * CD + c4 * 4;
    unsafeAtomicAdd(o + 0, v * yv.x);
    unsafeAtomicAdd(o + 1, v * yv.y);
    unsafeAtomicAdd(o + 2, v * yv.z);
    unsafeAtomicAdd(o + 3, v * yv.w);
}

extern "C" void kernel_launch(void* const* d_in, const int* in_sizes, int n_in,
                              void* d_out, int out_size, void* d_ws, size_t ws_size,
                              hipStream_t stream) {
    const float* x    = (const float*)d_in[0];
    const int*   rows = (const int*)d_in[1];
    const int*   cols = (const int*)d_in[2];
    const float* vals = (const float*)d_in[3];
    const float* Wm   = (const float*)d_in[4];
    const float* b    = (const float*)d_in[5];
    float* out = (float*)d_out;

    char* ws = (char*)d_ws;
    float* y       = (float*)(ws + Y_OFF);
    int*   counts  = (int*)(ws + CNT_OFF);
    int*   offsets = (int*)(ws + OFF_OFF);
    int*   cursor  = (int*)(ws + CUR_OFF);
    int*   bpre    = (int*)(ws + BPR_OFF);
    int*   sc      = (int*)(ws + SC_OFF);
    float* sv      = (float*)(ws + SV_OFF);

    gemm_xwT<<<NV / 32, 256, 0, stream>>>(x, Wm, y);   // 6250 blocks

    if (ws_size >= WS_REQ) {
        hipMemsetAsync(counts, 0, NV * sizeof(int), stream);
        k_hist<<<(NE + 255) / 256, 256, 0, stream>>>(rows, counts);
        k_blocksum<<<SCAN_NB, SCAN_BS, 0, stream>>>(counts, bpre /*reuse as bsum*/);
        k_scanpart<<<1, 256, 0, stream>>>(bpre, bpre, offsets);
        k_scan<<<SCAN_NB, SCAN_BS, 0, stream>>>(counts, bpre, offsets, cursor);
        k_permute<<<(NE + 255) / 256, 256, 0, stream>>>(rows, cols, vals, cursor, sc, sv);
        k_gather<<<(NV + 3) / 4, 256, 0, stream>>>(offsets, sc, sv, y, b, out);
    } else {
        bias_fill<<<(NV * CD / 4) / 256, 256, 0, stream>>>(b, out);
        scatter_edges<<<NE / 8, 256, 0, stream>>>(rows, cols, vals, y, out);
    }
}

// Round 4
// 374.066 us; speedup vs baseline: 7.4945x; 1.1127x over previous
//
#include <hip/hip_runtime.h>

#define NV 200000
#define NE 1600000
#define CD 128

// ---- workspace layout (bytes) ----
#define Y_OFF    0UL            // y bf16-packed: NV*CD*2 = 51,200,000
#define CNT_OFF  51200000UL     // NV ints
#define OFF_OFF  52000000UL     // NV+1 ints (padded)
#define CUR_OFF  52800256UL     // NV ints
#define BSUM_OFF 53600256UL     // 256 ints
#define SCAT_OFF 53601280UL     // NE int2 = 12,800,000
#define WS_REQ   66401280UL

#define SCAN_BS 1024
#define SCAN_NB ((NV + SCAN_BS - 1) / SCAN_BS)   // 196

__device__ __forceinline__ unsigned bf16pair(float a, float b) {
    unsigned ua = __float_as_uint(a);
    unsigned ub = __float_as_uint(b);
    ua += 0x7fffu + ((ua >> 16) & 1u);   // RNE
    ub += 0x7fffu + ((ub >> 16) & 1u);
    return (ua >> 16) | (ub & 0xffff0000u);
}

__device__ __forceinline__ void fma4(float4& acc, float xs, const float4& wv) {
    acc.x += xs * wv.x;
    acc.y += xs * wv.y;
    acc.z += xs * wv.z;
    acc.w += xs * wv.w;
}

// ---------------- Kernel 1: y(bf16) = x @ W^T ----------------
// 256 thr, 32 verts/block, W staged in two 64-k halves (48 KB LDS -> 3 blk/CU).
__global__ __launch_bounds__(256) void gemm_xwT(const float* __restrict__ x,
                                                const float* __restrict__ Wm,
                                                unsigned* __restrict__ y) {
    __shared__ __align__(16) float Xs[32 * CD];   // 16 KB
    __shared__ __align__(16) float Wt[64 * CD];   // 32 KB (one k-half, swizzled)

    const int t = threadIdx.x;
    const int v0 = blockIdx.x * 32;

    // stage X tile (fp32)
    {
        const float4* xg4 = reinterpret_cast<const float4*>(x + (size_t)v0 * CD);
        float4* Xs4w = reinterpret_cast<float4*>(Xs);
#pragma unroll
        for (int i = 0; i < 4; ++i) Xs4w[t + i * 256] = xg4[t + i * 256];
    }

    const int c4 = t & 31;          // channel quad 0..31
    const int vl0 = (t >> 5) * 4;   // local vertex base

    float4 a0 = {0, 0, 0, 0}, a1 = {0, 0, 0, 0}, a2 = {0, 0, 0, 0}, a3 = {0, 0, 0, 0};
    const float4* Xs4 = reinterpret_cast<const float4*>(Xs);
    const float4* Wt4 = reinterpret_cast<const float4*>(Wt);
    const float4* Wg4 = reinterpret_cast<const float4*>(Wm);

    for (int ks = 0; ks < 2; ++ks) {
        if (ks) __syncthreads();   // previous compute phase done reading Wt
        // stage W half: W[c][k], k in [64ks, 64ks+64), swizzled
        //   word (4*kkl+j)*128 + 4*((c>>2)^kkl) + (c&3)
#pragma unroll
        for (int i = 0; i < 8; ++i) {
            int idx = t + i * 256;       // 0..2047
            int c = idx >> 4;            // channel 0..127
            int kkl = idx & 15;          // local float4 index along k
            float4 wv = Wg4[c * 32 + 16 * ks + kkl];
            int col = 4 * ((c >> 2) ^ kkl) + (c & 3);
            Wt[(4 * kkl + 0) * CD + col] = wv.x;
            Wt[(4 * kkl + 1) * CD + col] = wv.y;
            Wt[(4 * kkl + 2) * CD + col] = wv.z;
            Wt[(4 * kkl + 3) * CD + col] = wv.w;
        }
        __syncthreads();

#pragma unroll 4
        for (int kkl = 0; kkl < 16; ++kkl) {
            const int ws = c4 ^ kkl;
            float4 w0 = Wt4[(4 * kkl + 0) * 32 + ws];
            float4 w1 = Wt4[(4 * kkl + 1) * 32 + ws];
            float4 w2 = Wt4[(4 * kkl + 2) * 32 + ws];
            float4 w3 = Wt4[(4 * kkl + 3) * 32 + ws];
            const int kg = 16 * ks + kkl;
            float4 x0 = Xs4[(vl0 + 0) * 32 + kg];
            float4 x1 = Xs4[(vl0 + 1) * 32 + kg];
            float4 x2 = Xs4[(vl0 + 2) * 32 + kg];
            float4 x3 = Xs4[(vl0 + 3) * 32 + kg];
            fma4(a0, x0.x, w0); fma4(a0, x0.y, w1); fma4(a0, x0.z, w2); fma4(a0, x0.w, w3);
            fma4(a1, x1.x, w0); fma4(a1, x1.y, w1); fma4(a1, x1.z, w2); fma4(a1, x1.w, w3);
            fma4(a2, x2.x, w0); fma4(a2, x2.y, w1); fma4(a2, x2.z, w2); fma4(a2, x2.w, w3);
            fma4(a3, x3.x, w0); fma4(a3, x3.y, w1); fma4(a3, x3.z, w2); fma4(a3, x3.w, w3);
        }
    }

    // pack to bf16 pairs: u32 j of row v holds channels (2j, 2j+1)
    uint2* y2 = reinterpret_cast<uint2*>(y);
    const size_t vb = (size_t)(v0 + vl0);
    y2[(vb + 0) * 32 + c4] = make_uint2(bf16pair(a0.x, a0.y), bf16pair(a0.z, a0.w));
    y2[(vb + 1) * 32 + c4] = make_uint2(bf16pair(a1.x, a1.y), bf16pair(a1.z, a1.w));
    y2[(vb + 2) * 32 + c4] = make_uint2(bf16pair(a2.x, a2.y), bf16pair(a2.z, a2.w));
    y2[(vb + 3) * 32 + c4] = make_uint2(bf16pair(a3.x, a3.y), bf16pair(a3.z, a3.w));
}

// ---------------- CSR build ----------------
__global__ __launch_bounds__(256) void k_hist(const int* __restrict__ rows,
                                              int* __restrict__ counts) {
    int e = blockIdx.x * 256 + threadIdx.x;
    if (e < NE) atomicAdd(&counts[rows[e]], 1);
}

// pass A: block-local exclusive scan; bsum[b] = block total
__global__ __launch_bounds__(SCAN_BS) void k_scanA(const int* __restrict__ counts,
                                                   int* __restrict__ offsets,
                                                   int* __restrict__ bsum) {
    __shared__ int s[SCAN_BS];
    int t = threadIdx.x;
    int i = blockIdx.x * SCAN_BS + t;
    int v = (i < NV) ? counts[i] : 0;
    s[t] = v;
    __syncthreads();
    for (int d = 1; d < SCAN_BS; d <<= 1) {
        int add = (t >= d) ? s[t - d] : 0;
        __syncthreads();
        s[t] += add;
        __syncthreads();
    }
    if (i < NV) offsets[i] = s[t] - v;
    if (t == SCAN_BS - 1) bsum[blockIdx.x] = s[t];
}

// pass B: every block redundantly scans bsum (196 entries), adds prefix
__global__ __launch_bounds__(SCAN_BS) void k_scanB(const int* __restrict__ bsum,
                                                   int* __restrict__ offsets,
                                                   int* __restrict__ cursor) {
    __shared__ int sb[256];
    int t = threadIdx.x;
    if (t < 256) sb[t] = (t < SCAN_NB) ? bsum[t] : 0;
    __syncthreads();
    for (int d = 1; d < 256; d <<= 1) {
        int add = 0;
        if (t < 256 && t >= d) add = sb[t - d];
        __syncthreads();
        if (t < 256) sb[t] += add;
        __syncthreads();
    }
    int bpre = (blockIdx.x == 0) ? 0 : sb[blockIdx.x - 1];
    int i = blockIdx.x * SCAN_BS + t;
    if (i < NV) {
        int o = offsets[i] + bpre;
        offsets[i] = o;
        cursor[i] = o;
    }
    if (blockIdx.x == 0 && t == 0) offsets[NV] = NE;
}

__global__ __launch_bounds__(256) void k_permute(const int* __restrict__ rows,
                                                 const int* __restrict__ cols,
                                                 const float* __restrict__ vals,
                                                 int* __restrict__ cursor,
                                                 int2* __restrict__ scat) {
    int e = blockIdx.x * 256 + threadIdx.x;
    if (e < NE) {
        int r = rows[e];
        int pos = atomicAdd(&cursor[r], 1);
        scat[pos] = make_int2(cols[e], __float_as_int(vals[e]));
    }
}

// ---------------- gather-reduce: 1 wave per row, bf16 y, unroll 4 ----------------
__global__ __launch_bounds__(256) void k_gather(const int* __restrict__ offsets,
                                                const int2* __restrict__ scat,
                                                const unsigned* __restrict__ y,
                                                const float* __restrict__ b,
                                                float* __restrict__ out) {
    const int wid = threadIdx.x >> 6;
    const int lane = threadIdx.x & 63;
    const int row = blockIdx.x * 4 + wid;

    float2 acc = reinterpret_cast<const float2*>(b)[lane];   // channels 2l, 2l+1

    int e = offsets[row];
    const int end = offsets[row + 1];

    for (; e + 4 <= end; e += 4) {
        int2 p0 = scat[e + 0];
        int2 p1 = scat[e + 1];
        int2 p2 = scat[e + 2];
        int2 p3 = scat[e + 3];
        unsigned u0 = y[(size_t)p0.x * 64 + lane];
        unsigned u1 = y[(size_t)p1.x * 64 + lane];
        unsigned u2 = y[(size_t)p2.x * 64 + lane];
        unsigned u3 = y[(size_t)p3.x * 64 + lane];
        float v0 = __int_as_float(p0.y), v1 = __int_as_float(p1.y);
        float v2 = __int_as_float(p2.y), v3 = __int_as_float(p3.y);
        acc.x += v0 * __uint_as_float(u0 << 16) + v1 * __uint_as_float(u1 << 16) +
                 v2 * __uint_as_float(u2 << 16) + v3 * __uint_as_float(u3 << 16);
        acc.y += v0 * __uint_as_float(u0 & 0xffff0000u) + v1 * __uint_as_float(u1 & 0xffff0000u) +
                 v2 * __uint_as_float(u2 & 0xffff0000u) + v3 * __uint_as_float(u3 & 0xffff0000u);
    }
    for (; e < end; ++e) {
        int2 p = scat[e];
        unsigned u = y[(size_t)p.x * 64 + lane];
        float v = __int_as_float(p.y);
        acc.x += v * __uint_as_float(u << 16);
        acc.y += v * __uint_as_float(u & 0xffff0000u);
    }
    reinterpret_cast<float2*>(out)[(size_t)row * 64 + lane] = acc;
}

extern "C" void kernel_launch(void* const* d_in, const int* in_sizes, int n_in,
                              void* d_out, int out_size, void* d_ws, size_t ws_size,
                              hipStream_t stream) {
    const float* x    = (const float*)d_in[0];
    const int*   rows = (const int*)d_in[1];
    const int*   cols = (const int*)d_in[2];
    const float* vals = (const float*)d_in[3];
    const float* Wm   = (const float*)d_in[4];
    const float* b    = (const float*)d_in[5];
    float* out = (float*)d_out;

    char* ws = (char*)d_ws;
    unsigned* y     = (unsigned*)(ws + Y_OFF);
    int* counts     = (int*)(ws + CNT_OFF);
    int* offsets    = (int*)(ws + OFF_OFF);
    int* cursor     = (int*)(ws + CUR_OFF);
    int* bsum       = (int*)(ws + BSUM_OFF);
    int2* scat      = (int2*)(ws + SCAT_OFF);

    gemm_xwT<<<NV / 32, 256, 0, stream>>>(x, Wm, y);                     // 6250
    hipMemsetAsync(counts, 0, NV * sizeof(int), stream);
    k_hist<<<NE / 256, 256, 0, stream>>>(rows, counts);                  // 6250
    k_scanA<<<SCAN_NB, SCAN_BS, 0, stream>>>(counts, offsets, bsum);     // 196
    k_scanB<<<SCAN_NB, SCAN_BS, 0, stream>>>(bsum, offsets, cursor);     // 196
    k_permute<<<NE / 256, 256, 0, stream>>>(rows, cols, vals, cursor, scat);
    k_gather<<<NV / 4, 256, 0, stream>>>(offsets, scat, y, b, out);      // 50000
}

// Round 5
// 287.698 us; speedup vs baseline: 9.7443x; 1.3002x over previous
//
#include <hip/hip_runtime.h>

#define NV 200000
#define NE 1600000
#define CD 128

// ---- workspace layout (bytes) ----
#define Y_OFF    0UL            // y bf16-packed: NV*CD*2 = 51,200,000
#define WB_OFF   51200000UL     // W bf16: 128*128*2 = 32768
#define CNT_OFF  51232768UL     // NV ints
#define OFF_OFF  52032768UL     // NV+1 ints (padded)
#define CUR_OFF  52833024UL     // NV ints
#define BSUM_OFF 53633024UL     // 1024 B
#define SCAT_OFF 53634048UL     // NE int2 = 12,800,000
#define WS_REQ   66434048UL

#define SCAN_BS 1024
#define SCAN_NB ((NV + SCAN_BS - 1) / SCAN_BS)   // 196

typedef short  short8 __attribute__((ext_vector_type(8)));
typedef float  f32x4  __attribute__((ext_vector_type(4)));

__device__ __forceinline__ short bf16of(float f) {
    __bf16 h = (__bf16)f;                 // RNE; compiler fuses pairs to v_cvt_pk_bf16_f32
    return __builtin_bit_cast(short, h);
}

// ---------------- Kernel 0: W fp32 -> bf16 (row-major [128][128]) ----------------
__global__ __launch_bounds__(256) void k_cvtW(const float* __restrict__ W,
                                              unsigned short* __restrict__ Wb) {
    int i = blockIdx.x * 256 + threadIdx.x;   // float4 index, 4096 total
    float4 wv = reinterpret_cast<const float4*>(W)[i];
    ushort4 o;
    o.x = (unsigned short)bf16of(wv.x);
    o.y = (unsigned short)bf16of(wv.y);
    o.z = (unsigned short)bf16of(wv.z);
    o.w = (unsigned short)bf16of(wv.w);
    reinterpret_cast<ushort4*>(Wb)[i] = o;
}

// ---------------- Kernel 1: y(bf16) = x @ W^T via MFMA ----------------
// A = W (chans x k), B = x^T (k x verts)  ->  D[chan][vert].
// C/D layout (m89): col(=vert)=lane&15, row(=chan)=(lane>>4)*4+reg.
// A/B fragment: lane&15 = row(A)/col(B); k-slots filled with the SAME bijection
// on both sides (k = 32*ks + (lane>>4)*8 + j), so the dot product is exact
// regardless of the HW's internal k ordering.
#define GEMM_BLOCKS 512
#define GEMM_WAVES (GEMM_BLOCKS * 4)      // 2048
#define NTILES (NV / 16)                  // 12500

__global__ __launch_bounds__(256, 2) void gemm_mfma(const float* __restrict__ x,
                                                    const unsigned short* __restrict__ Wb,
                                                    unsigned short* __restrict__ y) {
    __shared__ __align__(16) short Wlds[2048 * 8];   // 32 KB, fragment-linear

    const int t = threadIdx.x;
    const int lane = t & 63;
    const int w = t >> 6;
    const int g = lane >> 4;

    // stage W fragments into LDS: chunk c = (tile*4 + ks)*64 + lane
    {
        const uint4* Wg = reinterpret_cast<const uint4*>(Wb);   // 16 uint4 per row
        uint4* L = reinterpret_cast<uint4*>(Wlds);
#pragma unroll
        for (int i = 0; i < 8; ++i) {
            int c = t + i * 256;
            int l = c & 63;
            int ks = (c >> 6) & 3;
            int tl = c >> 8;
            int row = 16 * tl + (l & 15);
            L[c] = Wg[row * 16 + ks * 4 + (l >> 4)];
        }
    }
    __syncthreads();

    // hoist all 32 A-fragments (8 chan-tiles x 4 ksteps) into VGPRs: 128 regs
    short8 A[8][4];
    {
        const short8* L8 = reinterpret_cast<const short8*>(Wlds);
#pragma unroll
        for (int t8 = 0; t8 < 8; ++t8)
#pragma unroll
            for (int ks = 0; ks < 4; ++ks)
                A[t8][ks] = L8[(t8 * 4 + ks) * 64 + lane];
    }

    const int wgid = blockIdx.x * 4 + w;
    char* yb = reinterpret_cast<char*>(y);

    for (int tile = wgid; tile < NTILES; tile += GEMM_WAVES) {
        const int v0 = tile * 16;
        const int row = v0 + (lane & 15);
        const float4* xr = reinterpret_cast<const float4*>(x + (size_t)row * CD);

        // issue all 8 x-loads up front (8 KB/wave in flight)
        float4 xf[8];
#pragma unroll
        for (int ks = 0; ks < 4; ++ks) {
            xf[2 * ks]     = xr[8 * ks + 2 * g];
            xf[2 * ks + 1] = xr[8 * ks + 2 * g + 1];
        }

        f32x4 acc[8];
#pragma unroll
        for (int t8 = 0; t8 < 8; ++t8) acc[t8] = (f32x4){0.f, 0.f, 0.f, 0.f};

#pragma unroll
        for (int ks = 0; ks < 4; ++ks) {
            short8 B;
            const float* f = reinterpret_cast<const float*>(&xf[2 * ks]);
#pragma unroll
            for (int j = 0; j < 8; ++j) B[j] = bf16of(f[j]);
#pragma unroll
            for (int t8 = 0; t8 < 8; ++t8)
                acc[t8] = __builtin_amdgcn_mfma_f32_16x16x32_bf16(A[t8][ks], B, acc[t8], 0, 0, 0);
        }

        // store: lane's vert = v0+(lane&15); chans t8*16 + g*4 .. +3 (consecutive)
        const size_t rb = (size_t)(v0 + (lane & 15)) * 256;
#pragma unroll
        for (int t8 = 0; t8 < 8; ++t8) {
            ushort4 o;
            o.x = (unsigned short)bf16of(acc[t8][0]);
            o.y = (unsigned short)bf16of(acc[t8][1]);
            o.z = (unsigned short)bf16of(acc[t8][2]);
            o.w = (unsigned short)bf16of(acc[t8][3]);
            *reinterpret_cast<ushort4*>(yb + rb + t8 * 32 + g * 8) = o;
        }
    }
}

// ---------------- CSR build ----------------
__global__ __launch_bounds__(256) void k_hist(const int* __restrict__ rows,
                                              int* __restrict__ counts) {
    int e = blockIdx.x * 256 + threadIdx.x;
    if (e < NE) atomicAdd(&counts[rows[e]], 1);
}

__global__ __launch_bounds__(SCAN_BS) void k_scanA(const int* __restrict__ counts,
                                                   int* __restrict__ offsets,
                                                   int* __restrict__ bsum) {
    __shared__ int s[SCAN_BS];
    int t = threadIdx.x;
    int i = blockIdx.x * SCAN_BS + t;
    int v = (i < NV) ? counts[i] : 0;
    s[t] = v;
    __syncthreads();
    for (int d = 1; d < SCAN_BS; d <<= 1) {
        int add = (t >= d) ? s[t - d] : 0;
        __syncthreads();
        s[t] += add;
        __syncthreads();
    }
    if (i < NV) offsets[i] = s[t] - v;
    if (t == SCAN_BS - 1) bsum[blockIdx.x] = s[t];
}

__global__ __launch_bounds__(SCAN_BS) void k_scanB(const int* __restrict__ bsum,
                                                   int* __restrict__ offsets,
                                                   int* __restrict__ cursor) {
    __shared__ int sb[256];
    int t = threadIdx.x;
    if (t < 256) sb[t] = (t < SCAN_NB) ? bsum[t] : 0;
    __syncthreads();
    for (int d = 1; d < 256; d <<= 1) {
        int add = 0;
        if (t < 256 && t >= d) add = sb[t - d];
        __syncthreads();
        if (t < 256) sb[t] += add;
        __syncthreads();
    }
    int bpre = (blockIdx.x == 0) ? 0 : sb[blockIdx.x - 1];
    int i = blockIdx.x * SCAN_BS + t;
    if (i < NV) {
        int o = offsets[i] + bpre;
        offsets[i] = o;
        cursor[i] = o;
    }
    if (blockIdx.x == 0 && t == 0) offsets[NV] = NE;
}

__global__ __launch_bounds__(256) void k_permute(const int* __restrict__ rows,
                                                 const int* __restrict__ cols,
                                                 const float* __restrict__ vals,
                                                 int* __restrict__ cursor,
                                                 int2* __restrict__ scat) {
    int e = blockIdx.x * 256 + threadIdx.x;
    if (e < NE) {
        int r = rows[e];
        int pos = atomicAdd(&cursor[r], 1);
        scat[pos] = make_int2(cols[e], __float_as_int(vals[e]));
    }
}

// ---------------- gather-reduce: 1 wave per row, bf16 y, unroll 4 ----------------
__global__ __launch_bounds__(256) void k_gather(const int* __restrict__ offsets,
                                                const int2* __restrict__ scat,
                                                const unsigned* __restrict__ y,
                                                const float* __restrict__ b,
                                                float* __restrict__ out) {
    const int wid = threadIdx.x >> 6;
    const int lane = threadIdx.x & 63;
    const int row = blockIdx.x * 4 + wid;

    float2 acc = reinterpret_cast<const float2*>(b)[lane];   // channels 2l, 2l+1

    int e = offsets[row];
    const int end = offsets[row + 1];

    for (; e + 4 <= end; e += 4) {
        int2 p0 = scat[e + 0];
        int2 p1 = scat[e + 1];
        int2 p2 = scat[e + 2];
        int2 p3 = scat[e + 3];
        unsigned u0 = y[(size_t)p0.x * 64 + lane];
        unsigned u1 = y[(size_t)p1.x * 64 + lane];
        unsigned u2 = y[(size_t)p2.x * 64 + lane];
        unsigned u3 = y[(size_t)p3.x * 64 + lane];
        float v0 = __int_as_float(p0.y), v1 = __int_as_float(p1.y);
        float v2 = __int_as_float(p2.y), v3 = __int_as_float(p3.y);
        acc.x += v0 * __uint_as_float(u0 << 16) + v1 * __uint_as_float(u1 << 16) +
                 v2 * __uint_as_float(u2 << 16) + v3 * __uint_as_float(u3 << 16);
        acc.y += v0 * __uint_as_float(u0 & 0xffff0000u) + v1 * __uint_as_float(u1 & 0xffff0000u) +
                 v2 * __uint_as_float(u2 & 0xffff0000u) + v3 * __uint_as_float(u3 & 0xffff0000u);
    }
    for (; e < end; ++e) {
        int2 p = scat[e];
        unsigned u = y[(size_t)p.x * 64 + lane];
        float v = __int_as_float(p.y);
        acc.x += v * __uint_as_float(u << 16);
        acc.y += v * __uint_as_float(u & 0xffff0000u);
    }
    reinterpret_cast<float2*>(out)[(size_t)row * 64 + lane] = acc;
}

extern "C" void kernel_launch(void* const* d_in, const int* in_sizes, int n_in,
                              void* d_out, int out_size, void* d_ws, size_t ws_size,
                              hipStream_t stream) {
    const float* x    = (const float*)d_in[0];
    const int*   rows = (const int*)d_in[1];
    const int*   cols = (const int*)d_in[2];
    const float* vals = (const float*)d_in[3];
    const float* Wm   = (const float*)d_in[4];
    const float* b    = (const float*)d_in[5];
    float* out = (float*)d_out;

    char* ws = (char*)d_ws;
    unsigned short* y  = (unsigned short*)(ws + Y_OFF);
    unsigned short* Wb = (unsigned short*)(ws + WB_OFF);
    int* counts        = (int*)(ws + CNT_OFF);
    int* offsets       = (int*)(ws + OFF_OFF);
    int* cursor        = (int*)(ws + CUR_OFF);
    int* bsum          = (int*)(ws + BSUM_OFF);
    int2* scat         = (int2*)(ws + SCAT_OFF);

    k_cvtW<<<16, 256, 0, stream>>>(Wm, Wb);
    gemm_mfma<<<GEMM_BLOCKS, 256, 0, stream>>>(x, Wb, y);
    hipMemsetAsync(counts, 0, NV * sizeof(int), stream);
    k_hist<<<NE / 256, 256, 0, stream>>>(rows, counts);
    k_scanA<<<SCAN_NB, SCAN_BS, 0, stream>>>(counts, offsets, bsum);
    k_scanB<<<SCAN_NB, SCAN_BS, 0, stream>>>(bsum, offsets, cursor);
    k_permute<<<NE / 256, 256, 0, stream>>>(rows, cols, vals, cursor, scat);
    k_gather<<<NV / 4, 256, 0, stream>>>(offsets, scat, (const unsigned*)y, b, out);
}